// Round 11
// baseline (341.022 us; speedup 1.0000x reference)
//
#include <hip/hip_runtime.h>
#include <hip/hip_bf16.h>

#define NN 50000
#define EE 640000
#define ABLK 625   // pass A/B blocks
#define AEDG 1024  // edges per pass A/B block (625*1024 = 640000 exactly)
#define NBK 196    // buckets of 256 nodes (dst>>8)

typedef __attribute__((ext_vector_type(8))) short short8;
typedef __attribute__((ext_vector_type(4))) float f32x4;

__device__ __forceinline__ float bf2f(ushort u) {
    return __uint_as_float(((uint)u) << 16);
}
__device__ __forceinline__ ushort f2bf(float f) {
    uint b = __float_as_uint(f);
    uint r = (b + 0x7fffu + ((b >> 16) & 1u)) >> 16;
    return (ushort)r;
}
__device__ __forceinline__ ushort f2bf_rn(float f) {
    return (ushort)((__float_as_uint(f) + 0x8000u) >> 16);
}

// ---- Pass A: LDS bucket histogram + eab packing; tail blocks: compose -----

__global__ __launch_bounds__(256) void k_bucketA(
    const int* __restrict__ ei, const float* __restrict__ ea,
    uint* __restrict__ eab, int* __restrict__ bcnt,
    const float* __restrict__ wn_all, const float* __restrict__ aw1,
    const float* __restrict__ wle, ushort* __restrict__ wcT) {
    const int t = threadIdx.x;
    if (blockIdx.x >= ABLK) {
        const int bb = blockIdx.x - ABLK;
        const int l = bb >> 7;
        const int k = bb & 127;
        const float* wn = wn_all + (l * 128 + k) * 128;
        float acc = 0.f;
        for (int c = 0; c < 128; ++c) {
            float cat;
            if (t < 128)
                cat = aw1[(l * 256 + ((t & 64) << 1) + c) * 64 + (t & 63)];
            else
                cat = wle[(l * 130 + c) * 128 + (t - 128)];
            acc += wn[c] * cat;
        }
        wcT[(l * 256 + t) * 128 + k] = f2bf(acc);
        return;
    }
    __shared__ int h[NBK];
    for (int i = t; i < NBK; i += 256) h[i] = 0;
    __syncthreads();
    const int base = blockIdx.x * AEDG;
    #pragma unroll
    for (int k = 0; k < 4; ++k) {
        const int e = base + k * 256 + t;
        const int d = ei[EE + e];
        atomicAdd(&h[d >> 8], 1);
        const float2 v = *(const float2*)(ea + 2 * e);
        eab[e] = ((uint)f2bf(v.y) << 16) | (uint)f2bf(v.x);
    }
    __syncthreads();
    for (int i = t; i < NBK; i += 256)
        bcnt[i * ABLK + blockIdx.x] = h[i];
}

// ---- Scan 1: per-bucket exclusive scan over 625 block counts --------------

__global__ __launch_bounds__(256) void k_scanbkt(const int* __restrict__ bcnt,
                                                 int* __restrict__ boff2,
                                                 int* __restrict__ tot) {
    const int b = blockIdx.x;
    const int t = threadIdx.x;
    const int lane = t & 63, wv = t >> 6;
    __shared__ int ws[4];
    int run = 0;
    for (int k = 0; k < 3; ++k) {
        const int j = k * 256 + t;
        const int v = (j < ABLK) ? bcnt[b * ABLK + j] : 0;
        int x = v;
        #pragma unroll
        for (int o = 1; o < 64; o <<= 1) {
            int y = __shfl_up(x, o);
            if (lane >= o) x += y;
        }
        if (lane == 63) ws[wv] = x;
        __syncthreads();
        int add = 0;
        for (int w = 0; w < wv; ++w) add += ws[w];
        if (j < ABLK) boff2[b * ABLK + j] = run + add + x - v;
        const int btot = ws[0] + ws[1] + ws[2] + ws[3];
        __syncthreads();
        run += btot;
    }
    if (t == 0) tot[b] = run;
}

// ---- Scan 2: exclusive scan of bucket totals -> bbase ---------------------

__global__ __launch_bounds__(256) void k_scantot(const int* __restrict__ tot,
                                                 int* __restrict__ bbase) {
    const int t = threadIdx.x;
    const int lane = t & 63, wv = t >> 6;
    const int v = (t < NBK) ? tot[t] : 0;
    int x = v;
    #pragma unroll
    for (int o = 1; o < 64; o <<= 1) {
        int y = __shfl_up(x, o);
        if (lane >= o) x += y;
    }
    __shared__ int ws[4];
    if (lane == 63) ws[wv] = x;
    __syncthreads();
    int add = 0;
    for (int w = 0; w < wv; ++w) add += ws[w];
    if (t < NBK) bbase[t] = add + x - v;
    if (t == 255) bbase[NBK] = add + x;  // == EE
}

// ---- Pass B: bucket-partitioned staging (block-private contiguous ranges) -

__global__ __launch_bounds__(256) void k_bucketB(const int* __restrict__ ei,
                                                 const uint* __restrict__ eab,
                                                 const int* __restrict__ bbase,
                                                 const int* __restrict__ boff2,
                                                 uint2* __restrict__ staged) {
    __shared__ int cur[NBK];
    const int t = threadIdx.x;
    for (int i = t; i < NBK; i += 256)
        cur[i] = bbase[i] + boff2[i * ABLK + blockIdx.x];
    __syncthreads();
    const int base = blockIdx.x * AEDG;
    #pragma unroll
    for (int k = 0; k < 4; ++k) {
        const int e = base + k * 256 + t;
        const int d = ei[EE + e];
        const uint s = (uint)ei[e];
        const int pos = atomicAdd(&cur[d >> 8], 1);
        staged[pos] = make_uint2(s | ((uint)(d & 255) << 20), eab[e]);
    }
}

// ---- Pass C: per-bucket finalize: offs + adjSE (L2-local) -----------------

__global__ __launch_bounds__(256) void k_bucketC(const int* __restrict__ bbase,
                                                 const uint2* __restrict__ staged,
                                                 uint2* __restrict__ adjSE,
                                                 int* __restrict__ offs) {
    const int b = blockIdx.x;
    const int t = threadIdx.x;
    const int lane = t & 63, wv = t >> 6;
    const int sbeg = bbase[b], send = bbase[b + 1];

    __shared__ int cnt[256];
    __shared__ int cur[256];
    __shared__ int ws[4];
    cnt[t] = 0;
    __syncthreads();
    for (int i = sbeg + t; i < send; i += 256)
        atomicAdd(&cnt[(staged[i].x >> 20) & 255], 1);
    __syncthreads();

    const int v = cnt[t];
    int x = v;
    #pragma unroll
    for (int o = 1; o < 64; o <<= 1) {
        int y = __shfl_up(x, o);
        if (lane >= o) x += y;
    }
    if (lane == 63) ws[wv] = x;
    __syncthreads();
    int add = 0;
    for (int w = 0; w < wv; ++w) add += ws[w];
    const int excl = add + x - v;

    const int node = b * 256 + t;
    if (node <= NN) offs[node] = sbeg + excl;
    cur[t] = sbeg + excl;
    __syncthreads();

    for (int i = sbeg + t; i < send; i += 256) {
        const uint2 r = staged[i];
        const int din = (r.x >> 20) & 255;
        const int pos = atomicAdd(&cur[din], 1);
        adjSE[pos] = make_uint2(r.x & 0xFFFFFu, r.y);
    }
}

// ---- K1: pqr = x @ Wc   [N,128]x[128,256] -> bf16 [N,256] -----------------
// 64 rows/block, B in registers, A prefetched one row-tile ahead.

#define K1_LOADA(AV, RT)                                                   \
    {                                                                      \
        const float* xrow_ = xin + (size_t)(rbase + (RT) * 16 + lrow) * 128; \
        _Pragma("unroll")                                                  \
        for (int s = 0; s < 4; ++s) {                                      \
            const float* px = xrow_ + s * 32 + kg * 8;                     \
            float4 u = *(const float4*)(px);                               \
            float4 v = *(const float4*)(px + 4);                           \
            short8 av;                                                     \
            av[0] = (short)f2bf(u.x); av[1] = (short)f2bf(u.y);            \
            av[2] = (short)f2bf(u.z); av[3] = (short)f2bf(u.w);            \
            av[4] = (short)f2bf(v.x); av[5] = (short)f2bf(v.y);            \
            av[6] = (short)f2bf(v.z); av[7] = (short)f2bf(v.w);            \
            AV[s] = av;                                                    \
        }                                                                  \
    }

#define K1_COMP(AV, RT)                                                    \
    {                                                                      \
        f32x4 acc[4] = {};                                                 \
        _Pragma("unroll")                                                  \
        for (int t = 0; t < 4; ++t) {                                      \
            _Pragma("unroll")                                              \
            for (int s = 0; s < 4; ++s)                                    \
                acc[t] = __builtin_amdgcn_mfma_f32_16x16x32_bf16(          \
                    AV[s], b[t][s], acc[t], 0, 0, 0);                      \
        }                                                                  \
        _Pragma("unroll")                                                  \
        for (int t = 0; t < 4; ++t) {                                      \
            const int col = c0 + t * 16 + lrow;                            \
            _Pragma("unroll")                                              \
            for (int j = 0; j < 4; ++j)                                    \
                pqr[(size_t)(rbase + (RT) * 16 + kg * 4 + j) * 256 + col] = \
                    f2bf(acc[t][j]);                                       \
        }                                                                  \
    }

__global__ __launch_bounds__(256) void k1_gemm(const float* __restrict__ xin,
                                               const ushort* __restrict__ wcT,
                                               ushort* __restrict__ pqr) {
    const int wave = threadIdx.x >> 6;
    const int lane = threadIdx.x & 63;
    const int rbase = blockIdx.x * 64;
    const int c0 = wave * 64;
    const int lrow = lane & 15;
    const int kg = lane >> 4;

    short8 b[4][4];
    #pragma unroll
    for (int t = 0; t < 4; ++t) {
        const int col = c0 + t * 16 + lrow;
        #pragma unroll
        for (int s = 0; s < 4; ++s)
            b[t][s] = *(const short8*)(wcT + col * 128 + s * 32 + kg * 8);
    }

    if (rbase + 64 <= NN) {
        short8 aA[4], aB[4];
        K1_LOADA(aA, 0)
        K1_LOADA(aB, 1) K1_COMP(aA, 0)
        K1_LOADA(aA, 2) K1_COMP(aB, 1)
        K1_LOADA(aB, 3) K1_COMP(aA, 2)
        K1_COMP(aB, 3)
    } else {
        #pragma unroll
        for (int rt = 0; rt < 4; ++rt) {
            const int r0 = rbase + rt * 16;
            int arow = r0 + lrow;
            if (arow >= NN) arow = NN - 1;
            const float* xrow = xin + (size_t)arow * 128;
            short8 a[4];
            #pragma unroll
            for (int s = 0; s < 4; ++s) {
                const float* px = xrow + s * 32 + kg * 8;
                float4 u = *(const float4*)(px);
                float4 v = *(const float4*)(px + 4);
                short8 av;
                av[0] = (short)f2bf(u.x); av[1] = (short)f2bf(u.y);
                av[2] = (short)f2bf(u.z); av[3] = (short)f2bf(u.w);
                av[4] = (short)f2bf(v.x); av[5] = (short)f2bf(v.y);
                av[6] = (short)f2bf(v.z); av[7] = (short)f2bf(v.w);
                a[s] = av;
            }
            f32x4 acc[4] = {};
            #pragma unroll
            for (int t = 0; t < 4; ++t) {
                #pragma unroll
                for (int s = 0; s < 4; ++s)
                    acc[t] = __builtin_amdgcn_mfma_f32_16x16x32_bf16(a[s], b[t][s], acc[t], 0, 0, 0);
            }
            #pragma unroll
            for (int t = 0; t < 4; ++t) {
                const int col = c0 + t * 16 + lrow;
                #pragma unroll
                for (int j = 0; j < 4; ++j) {
                    const int orow = r0 + kg * 4 + j;
                    if (orow < NN)
                        pqr[(size_t)orow * 256 + col] = f2bf(acc[t][j]);
                }
            }
        }
    }
}

// ---- K_fused: attention (MFMA) + aggregation + epilogue, 1 wave/node ------
// Per 16-edge chunk: q-gather -> A=relu(q+(p[dst]+b1)) -> 2 MFMA vs w2 ->
// sigmoid scores in regs -> 16-edge r-phase with compile-time-lane shfl
// broadcasts (no LDS, no cross-wave sync).

__global__ __launch_bounds__(256) void k_fused(
    const int* __restrict__ offs, const uint2* __restrict__ adjSE,
    const ushort* __restrict__ pqr, const float* __restrict__ xin,
    const float* __restrict__ b1v, const float* __restrict__ w2v,
    const float* __restrict__ b2v, const float* __restrict__ web,
    const float* __restrict__ biasv, const float* __restrict__ gammav,
    const float* __restrict__ betav, float* __restrict__ xout, int do_relu) {
    const int lane = threadIdx.x & 63;
    const int n = blockIdx.x * 4 + (threadIdx.x >> 6);
    const int c0 = 2 * lane;
    const int row = lane & 15;
    const int kg = lane >> 4;

    const int eb = __builtin_amdgcn_readfirstlane(offs[n]);
    const int ee = __builtin_amdgcn_readfirstlane(offs[n + 1]);
    const int cnt = ee - eb;

    float acc0 = 0.f, acc1 = 0.f, sE0 = 0.f, sE1 = 0.f;

    if (cnt > 0) {
        const float b2 = b2v[0];
        short8 bv0, bv1;
        const bool col0 = (row == 0);
        #pragma unroll
        for (int j = 0; j < 8; ++j) {
            bv0[j] = (short)f2bf(col0 ? w2v[kg * 8 + j] : 0.f);
            bv1[j] = (short)f2bf(col0 ? w2v[32 + kg * 8 + j] : 0.f);
        }
        float pb0[8], pb1[8];
        {
            short8 p0 = *(const short8*)(pqr + (size_t)n * 256 + kg * 8);
            short8 p1 = *(const short8*)(pqr + (size_t)n * 256 + 32 + kg * 8);
            #pragma unroll
            for (int j = 0; j < 8; ++j) {
                pb0[j] = bf2f((ushort)p0[j]) + b1v[kg * 8 + j];
                pb1[j] = bf2f((ushort)p1[j]) + b1v[32 + kg * 8 + j];
            }
        }

        for (int cb = 0; cb < cnt; cb += 16) {
            const int e = eb + cb + row;
            const int ec = e < ee ? e : (ee - 1);
            const uint2 m = adjSE[ec];
            const ushort* qp = pqr + (size_t)m.x * 256 + 64;
            const short8 q0 = *(const short8*)(qp + kg * 8);
            const short8 q1 = *(const short8*)(qp + 32 + kg * 8);
            short8 av0, av1;
            #pragma unroll
            for (int j = 0; j < 8; ++j) {
                av0[j] = (short)f2bf_rn(fmaxf(bf2f((ushort)q0[j]) + pb0[j], 0.f));
                av1[j] = (short)f2bf_rn(fmaxf(bf2f((ushort)q1[j]) + pb1[j], 0.f));
            }
            f32x4 sc = {};
            sc = __builtin_amdgcn_mfma_f32_16x16x32_bf16(av0, bv0, sc, 0, 0, 0);
            sc = __builtin_amdgcn_mfma_f32_16x16x32_bf16(av1, bv1, sc, 0, 0, 0);
            // scores for edges cb+kg*4+j live in sc[j] of lanes with row==0
            const float at0 = (cb + kg * 4 + 0 < cnt) ? 1.f / (1.f + __expf(-(sc[0] + b2))) : 0.f;
            const float at1 = (cb + kg * 4 + 1 < cnt) ? 1.f / (1.f + __expf(-(sc[1] + b2))) : 0.f;
            const float at2 = (cb + kg * 4 + 2 < cnt) ? 1.f / (1.f + __expf(-(sc[2] + b2))) : 0.f;
            const float at3 = (cb + kg * 4 + 3 < cnt) ? 1.f / (1.f + __expf(-(sc[3] + b2))) : 0.f;

            #pragma unroll
            for (int ce = 0; ce < 16; ++ce) {
                const float atx = (ce & 3) == 0 ? at0
                                : (ce & 3) == 1 ? at1
                                : (ce & 3) == 2 ? at2 : at3;
                const float att = __shfl(atx, (ce >> 2) * 16);
                const uint my = __shfl(m.y, ce);
                const uint srcb = __shfl(m.x, ce);
                const uint rv = *((const uint*)(pqr + (size_t)srcb * 256 + 128) + lane);
                acc0 = fmaf(att, __uint_as_float(rv << 16), acc0);
                acc1 = fmaf(att, __uint_as_float(rv & 0xffff0000u), acc1);
                sE0 = fmaf(att, __uint_as_float(my << 16), sE0);
                sE1 = fmaf(att, __uint_as_float(my & 0xffff0000u), sE1);
            }
        }
    }

    const float web00 = web[c0], web01 = web[c0 + 1];
    const float web10 = web[128 + c0], web11 = web[128 + c0 + 1];
    acc0 += sE0 * web00 + sE1 * web10;
    acc1 += sE0 * web01 + sE1 * web11;

    const float2 bi = *(const float2*)(biasv + c0);
    float v0 = acc0 + bi.x;
    float v1 = acc1 + bi.y;
    float sm = v0 + v1, sq = v0 * v0 + v1 * v1;
    #pragma unroll
    for (int o = 32; o > 0; o >>= 1) {
        sm += __shfl_xor(sm, o);
        sq += __shfl_xor(sq, o);
    }
    const float mean = sm * (1.f / 128.f);
    const float var = sq * (1.f / 128.f) - mean * mean;
    const float inv = rsqrtf(var + 1e-5f);
    const float2 ga = *(const float2*)(gammav + c0);
    const float2 be = *(const float2*)(betav + c0);
    float y0 = (v0 - mean) * inv * ga.x + be.x;
    float y1 = (v1 - mean) * inv * ga.y + be.y;
    if (do_relu) { y0 = fmaxf(y0, 0.f); y1 = fmaxf(y1, 0.f); }
    const float2 xr = *(const float2*)(xin + (size_t)n * 128 + c0);
    y0 += xr.x;
    y1 += xr.y;
    float2 o2; o2.x = y0; o2.y = y1;
    *(float2*)(xout + (size_t)n * 128 + c0) = o2;
}

// ---------------------------------------------------------------------------

extern "C" void kernel_launch(void* const* d_in, const int* in_sizes, int n_in,
                              void* d_out, int out_size, void* d_ws, size_t ws_size,
                              hipStream_t stream) {
    const float* x   = (const float*)d_in[0];
    const int*   ei  = (const int*)d_in[1];
    const float* ea  = (const float*)d_in[2];
    const float* wn  = (const float*)d_in[3];
    const float* wle = (const float*)d_in[4];
    const float* aw1 = (const float*)d_in[5];
    const float* ab1 = (const float*)d_in[6];
    const float* aw2 = (const float*)d_in[7];
    const float* ab2 = (const float*)d_in[8];
    const float* bia = (const float*)d_in[9];
    const float* gam = (const float*)d_in[10];
    const float* bet = (const float*)d_in[11];

    char* w = (char*)d_ws;
    size_t o = 0;
    auto alloc = [&](size_t bytes) {
        char* p = w + o;
        o = (o + bytes + 255) & ~(size_t)255;
        return p;
    };
    int*    offs    = (int*)alloc((size_t)(NN + 1) * 4);
    int*    bcnt    = (int*)alloc((size_t)NBK * ABLK * 4);
    int*    boff2   = (int*)alloc((size_t)NBK * ABLK * 4);
    int*    tot     = (int*)alloc((size_t)NBK * 4);
    int*    bbase   = (int*)alloc((size_t)(NBK + 1) * 4);
    uint*   eab     = (uint*)alloc((size_t)EE * 4);
    uint2*  staged  = (uint2*)alloc((size_t)EE * 8);
    uint2*  adjSE   = (uint2*)alloc((size_t)EE * 8);
    ushort* wcT     = (ushort*)alloc((size_t)3 * 256 * 128 * 2);
    ushort* pqr     = (ushort*)alloc((size_t)NN * 256 * 2);
    float*  xb1     = (float*)alloc((size_t)NN * 128 * 4);
    float*  xb2     = (float*)alloc((size_t)NN * 128 * 4);

    k_bucketA<<<ABLK + 384, 256, 0, stream>>>(ei, ea, eab, bcnt, wn, aw1, wle, wcT);
    k_scanbkt<<<NBK, 256, 0, stream>>>(bcnt, boff2, tot);
    k_scantot<<<1, 256, 0, stream>>>(tot, bbase);
    k_bucketB<<<ABLK, 256, 0, stream>>>(ei, eab, bbase, boff2, staged);
    k_bucketC<<<NBK, 256, 0, stream>>>(bbase, staged, adjSE, offs);

    const float* xi = x;
    float* xo = xb1;
    for (int l = 0; l < 3; ++l) {
        k1_gemm<<<(NN + 63) / 64, 256, 0, stream>>>(xi, wcT + (size_t)l * 256 * 128, pqr);
        const bool last = (l == 2);
        float* out_ptr = last ? (float*)d_out : xo;
        k_fused<<<NN / 4, 256, 0, stream>>>(
            offs, adjSE, pqr, xi,
            ab1 + l * 64, aw2 + l * 64, ab2 + l,
            wle + ((size_t)l * 130 + 128) * 128,
            bia + l * 128, gam + l * 128, bet + l * 128,
            out_ptr, last ? 0 : 1);
        xi = out_ptr;
        xo = (l == 0) ? xb2 : xb1;
    }
}